// Round 14
// baseline (604.646 us; speedup 1.0000x reference)
//
#include <hip/hip_runtime.h>
#include <math.h>

// ---------------- problem constants ----------------
#define BATCH 32768
#define HID   512
#define NOBJ  5
#define MTOT  (NOBJ*BATCH)   // 163840 total rows
#define TM    64             // fused-path rows per block
#define NBT   (BATCH/TM)

typedef __attribute__((ext_vector_type(8))) short bf16x8;
typedef __attribute__((ext_vector_type(4))) float f32x4;

typedef const __attribute__((address_space(1))) void* gas1_t;
typedef __attribute__((address_space(3))) void* las3_t;

__device__ __constant__ int d_OIDS[5][12] = {
  {0,1,2,3, 10,11,12,13,14,18,22,26},
  {0,4,5,6, 10,14,15,16,17,19,23,27},
  {1,4,7,8, 11,15,18,19,20,21,24,28},
  {2,5,7,9, 12,16,20,22,23,24,25,29},
  {3,6,8,9, 13,17,21,25,26,27,28,29}
};

// ---------------- bf16 weight workspace (ushort offsets) ----------------
#define UO_EW0   0                       // [512][64]  (K padded 44->64)
#define UO_EW1   (UO_EW0 + 512*64)       // [512][512]
#define UO_HEADS (UO_EW1 + 512*512)      // [32][512]: rows 0-8 Wm, 16-24 Wv
#define UO_DW0   (UO_HEADS + 32*512)     // [512][64]  (K padded 41->64)
#define UO_DW1   (UO_DW0 + 512*64)       // [512][512]
#define UO_DW2   (UO_DW1 + 512*512)      // [16][512]: rows 0-11 dec_W2
#define UO_TOTAL (UO_DW2 + 16*512)       // 614400 ushorts = 1.23 MB

// ---------------- output layout (floats) ----------------
#define OUT_MEANS (BATCH*30)
#define OUT_LV    (OUT_MEANS + NOBJ*BATCH*9)
#define OUT_Z     (OUT_LV    + NOBJ*BATCH*9)

__device__ __forceinline__ unsigned short f2b(float x) {
  unsigned int u = __builtin_bit_cast(unsigned int, x);
  u += 0x7FFFu + ((u >> 16) & 1u);
  return (unsigned short)(u >> 16);
}

// ---------------- prep: convert/pad weights into ws (bf16) ----------------
__global__ void __launch_bounds__(256)
prep_bf16(const float* __restrict__ eW0, const float* __restrict__ eW1,
          const float* __restrict__ Wm,  const float* __restrict__ Wv,
          const float* __restrict__ dW0, const float* __restrict__ dW1,
          const float* __restrict__ dW2, unsigned short* __restrict__ ws)
{
  for (int i = blockIdx.x*blockDim.x + threadIdx.x; i < UO_TOTAL; i += gridDim.x*blockDim.x) {
    float v = 0.f; int j;
    if (i < UO_EW1) {
      j = i - UO_EW0; int h = j >> 6, k = j & 63;
      if (k < 44) v = eW0[h*44 + k];
    } else if (i < UO_HEADS) {
      j = i - UO_EW1; v = eW1[j];
    } else if (i < UO_DW0) {
      j = i - UO_HEADS; int r = j >> 9, k = j & 511;
      if (r < 9)                  v = Wm[r*512 + k];
      else if (r >= 16 && r < 25) v = Wv[(r-16)*512 + k];
    } else if (i < UO_DW1) {
      j = i - UO_DW0; int h = j >> 6, k = j & 63;
      if (k < 41) v = dW0[h*41 + k];
    } else if (i < UO_DW2) {
      j = i - UO_DW1; v = dW1[j];
    } else {
      j = i - UO_DW2; int r = j >> 9, k = j & 511;
      if (r < 12) v = dW2[r*512 + k];
    }
    ws[i] = f2b(v);
  }
}

// =====================================================================
// ===================== LAYER-WISE PATH (big ws) ======================
// =====================================================================

// ---- stage one [128 rows][32 k] tile into LDS, conflict-free chunks ----
// chunk c (16B) = ((rowHi*4+kg)*16 + rowLo): row = rowHi*16+rowLo, k = kg*8..+8.
// LDS dest LINEAR (chunk c at byte c*16); permutation lives in the per-lane
// GLOBAL source address (rule 21; r8-verified conflict-free on read).
template<int KT>
__device__ __forceinline__ void stage_tile(const unsigned short* __restrict__ src,
                                           unsigned short* buf, int kt, int t)
{
  #pragma unroll
  for (int i = 0; i < 2; ++i) {
    const int c   = i*256 + t;
    const int row = ((c >> 6) << 4) | (c & 15);
    const int kg  = (c >> 4) & 3;
    const unsigned short* g = src + (size_t)row*(KT*32) + kt*32 + kg*8;
    unsigned short* l = buf + (size_t)(i*256 + (t & ~63)) * 8;
    __builtin_amdgcn_global_load_lds((gas1_t)g, (las3_t)l, 16, 0, 0);
  }
}

// C[Mc][512] = relu(A[Mc][KT*32] @ W[512][KT*32]^T + bias)
// m97-verified structure: 128x128 tile, 256 thr / 4 waves (2Mx2N), acc[4][4],
// A+B double-buffered via global_load_lds, 2-barrier K-loop, XCD swizzle.
template<int KT>
__global__ void __launch_bounds__(256, 2)
gemm_k(const unsigned short* __restrict__ A, const unsigned short* __restrict__ W,
       const float* __restrict__ bias, unsigned short* __restrict__ C, int nwg)
{
  __shared__ __align__(16) unsigned short sT[4*4096];  // A0 A1 B0 B1 (32 KB)

  const int t = threadIdx.x;
  const int wave = t >> 6, lane = t & 63;
  const int wm = wave >> 1, wn = wave & 1;
  const int lcol = lane & 15, kg = lane >> 4, rbase = kg*4;
  const int cpx = nwg >> 3;                       // nwg % 8 == 0
  const int sid = ((int)blockIdx.x & 7)*cpx + ((int)blockIdx.x >> 3);
  const int mtile = sid >> 2, ntile = sid & 3;

  const unsigned short* Ab = A + (size_t)mtile*128*(KT*32);
  const unsigned short* Wb = W + (size_t)ntile*128*(KT*32);

  f32x4 acc[4][4];
  #pragma unroll
  for (int n = 0; n < 4; ++n) {
    const float bv = bias[ntile*128 + wn*64 + n*16 + lcol];
    #pragma unroll
    for (int m = 0; m < 4; ++m) acc[m][n] = (f32x4){bv, bv, bv, bv};
  }

  stage_tile<KT>(Ab, sT,          0, t);
  stage_tile<KT>(Wb, sT + 2*4096, 0, t);
  __syncthreads();

  int cur = 0;
  #pragma unroll 1
  for (int kt = 0; kt < KT; ++kt) {
    if (kt + 1 < KT) {
      stage_tile<KT>(Ab, sT + (cur^1)*4096,          kt+1, t);
      stage_tile<KT>(Wb, sT + 2*4096 + (cur^1)*4096, kt+1, t);
    }
    const unsigned short* bufA = sT + cur*4096;
    const unsigned short* bufB = sT + 2*4096 + cur*4096;
    bf16x8 a[4], b[4];
    #pragma unroll
    for (int m = 0; m < 4; ++m)
      a[m] = *(const bf16x8*)&bufA[(((wm*4+m)*4 + kg)*16 + lcol)*8];
    #pragma unroll
    for (int n = 0; n < 4; ++n)
      b[n] = *(const bf16x8*)&bufB[(((wn*4+n)*4 + kg)*16 + lcol)*8];
    #pragma unroll
    for (int n = 0; n < 4; ++n)
      #pragma unroll
      for (int m = 0; m < 4; ++m)
        acc[m][n] = __builtin_amdgcn_mfma_f32_16x16x32_bf16(a[m], b[n], acc[m][n], 0, 0, 0);
    __syncthreads();
    cur ^= 1;
  }

  // epilogue: relu -> LDS bounce (32 KB [128][128] bf16) -> coalesced 16B stores
  unsigned short* sC = sT;
  #pragma unroll
  for (int m = 0; m < 4; ++m)
    #pragma unroll
    for (int n = 0; n < 4; ++n) {
      const int col = wn*64 + n*16 + lcol;
      #pragma unroll
      for (int r = 0; r < 4; ++r) {
        const int row = wm*64 + m*16 + rbase + r;
        sC[row*128 + (col ^ ((row & 7) << 3))] = f2b(fmaxf(acc[m][n][r], 0.f));
      }
    }
  __syncthreads();
  #pragma unroll
  for (int i = 0; i < 8; ++i) {
    const int g = i*256 + t;
    const int row = g >> 4, c0 = (g & 15)*8;
    bf16x8 v = *(const bf16x8*)&sC[row*128 + (c0 ^ ((row & 7) << 3))];
    *(bf16x8*)&C[(size_t)(mtile*128 + row)*512 + ntile*128 + c0] = v;
  }
}

// ---- encoder input builder: X[lrow][64] = [oh|s|gi|gc|0], plain row-major ----
__global__ void __launch_bounds__(256)
enc_in_k(const float* __restrict__ ic, const float* __restrict__ is_,
         const float* __restrict__ cc, unsigned short* __restrict__ X, int M0)
{
  #pragma unroll
  for (int i = 0; i < 16; ++i) {
    const int idx = i*256 + threadIdx.x;
    const int lrow = blockIdx.x*64 + (idx >> 6), col = idx & 63;
    const int grow = M0 + lrow, o = grow >> 15, b = grow & 32767;
    float v = 0.f;
    if (col < 5)       v = (col == o) ? 1.f : 0.f;
    else if (col < 20) v = is_[b*15 + col - 5];
    else if (col < 32) v = ic[b*30 + d_OIDS[o][col-20]];
    else if (col < 44) v = cc[b*30 + d_OIDS[o][col-32]];
    X[(size_t)lrow*64 + col] = f2b(v);
  }
}

// ---- decoder input (non-z cols): D[lrow][64] = [oh|_z_|s|gi|0] ----
__global__ void __launch_bounds__(256)
dec_in_k(const float* __restrict__ ic, const float* __restrict__ is_,
         unsigned short* __restrict__ D, int M0)
{
  #pragma unroll
  for (int i = 0; i < 16; ++i) {
    const int idx = i*256 + threadIdx.x;
    const int lrow = blockIdx.x*64 + (idx >> 6), col = idx & 63;
    if (col >= 5 && col < 14) continue;      // z written by heads_k
    const int grow = M0 + lrow, o = grow >> 15, b = grow & 32767;
    float v = 0.f;
    if (col < 5)       v = (col == o) ? 1.f : 0.f;
    else if (col < 29) v = is_[b*15 + col - 14];
    else if (col < 41) v = ic[b*30 + d_OIDS[o][col-29]];
    D[(size_t)lrow*64 + col] = f2b(v);
  }
}

// ---- heads: means/lv/z from H2 (direct global A reads), z -> D, outs coalesced ----
__global__ void __launch_bounds__(256)
heads_k(const unsigned short* __restrict__ H2, unsigned short* __restrict__ D,
        const float* __restrict__ eps, const float* __restrict__ bm,
        const float* __restrict__ bv, const unsigned short* __restrict__ ws,
        float* __restrict__ out, int M0)
{
  __shared__ float stage[3*64*9];
  const int t = threadIdx.x, wave = t >> 6, lane = t & 63;
  const int lcol = lane & 15, kg = lane >> 4, lk = kg*8, rbase = kg*4;
  const int lrow0 = blockIdx.x*64;
  const float bmv = (lcol < 9) ? bm[lcol] : 0.f;
  const float bvv = (lcol < 9) ? bv[lcol] : 0.f;
  f32x4 am = (f32x4){bmv, bmv, bmv, bmv};
  f32x4 av = (f32x4){bvv, bvv, bvv, bvv};
  const unsigned short* hpM = ws + UO_HEADS + lcol*512 + lk;
  const unsigned short* hpV = hpM + 16*512;
  const unsigned short* ap  = H2 + (size_t)(lrow0 + wave*16 + lcol)*512 + lk;
  bf16x8 m0 = *(const bf16x8*)hpM;
  bf16x8 v0 = *(const bf16x8*)hpV;
  #pragma unroll 1
  for (int kt = 0; kt < 16; ++kt) {
    bf16x8 m1 = m0, v1 = v0;
    if (kt + 1 < 16) {
      m1 = *(const bf16x8*)(hpM + (kt+1)*32);
      v1 = *(const bf16x8*)(hpV + (kt+1)*32);
    }
    bf16x8 a = *(const bf16x8*)(ap + kt*32);
    am = __builtin_amdgcn_mfma_f32_16x16x32_bf16(a, m0, am, 0, 0, 0);
    av = __builtin_amdgcn_mfma_f32_16x16x32_bf16(a, v0, av, 0, 0, 0);
    m0 = m1; v0 = v1;
  }
  if (lcol < 9) {
    #pragma unroll
    for (int r = 0; r < 4; ++r) {
      const int sr = wave*16 + rbase + r;          // 0..63 in block
      const int grow = M0 + lrow0 + sr;
      const float m_ = am[r], v_ = av[r];
      const float zz = fmaf(eps[(size_t)grow*9 + lcol], expf(0.5f*v_), m_);
      stage[       sr*9 + lcol] = m_;
      stage[576 +  sr*9 + lcol] = v_;
      stage[1152 + sr*9 + lcol] = zz;
      D[(size_t)(lrow0 + sr)*64 + 5 + lcol] = f2b(zz);
    }
  }
  __syncthreads();
  const size_t gb = (size_t)(M0 + lrow0)*9;
  for (int i = t; i < 576; i += 256) {
    out[OUT_MEANS + gb + i] = stage[i];
    out[OUT_LV    + gb + i] = stage[576 + i];
    out[OUT_Z     + gb + i] = stage[1152 + i];
  }
}

// ---- dec head: G2 @ dW2 + sigmoid + atomic scatter into out[B][30] ----
__global__ void __launch_bounds__(256)
dec_head_k(const unsigned short* __restrict__ G2, const unsigned short* __restrict__ ws,
           const float* __restrict__ db2, float* __restrict__ out, int M0)
{
  const int t = threadIdx.x, wave = t >> 6, lane = t & 63;
  const int lcol = lane & 15, kg = lane >> 4, lk = kg*8, rbase = kg*4;
  const int lrow0 = blockIdx.x*64;
  const float b2 = (lcol < 12) ? db2[lcol] : 0.f;
  f32x4 acc = (f32x4){b2, b2, b2, b2};
  const unsigned short* wp = ws + UO_DW2 + lcol*512 + lk;
  const unsigned short* ap = G2 + (size_t)(lrow0 + wave*16 + lcol)*512 + lk;
  bf16x8 b0 = *(const bf16x8*)wp;
  #pragma unroll 1
  for (int kt = 0; kt < 16; ++kt) {
    bf16x8 b1 = b0;
    if (kt + 1 < 16) b1 = *(const bf16x8*)(wp + (kt+1)*32);
    bf16x8 a = *(const bf16x8*)(ap + kt*32);
    acc = __builtin_amdgcn_mfma_f32_16x16x32_bf16(a, b0, acc, 0, 0, 0);
    b0 = b1;
  }
  if (lcol < 12) {
    #pragma unroll
    for (int r = 0; r < 4; ++r) {
      const int grow = M0 + lrow0 + wave*16 + rbase + r;
      const int o = grow >> 15, b = grow & 32767;
      atomicAdd(&out[b*30 + d_OIDS[o][lcol]], 1.f / (1.f + expf(-acc[r])));
    }
  }
}

// =====================================================================
// ================= FUSED FALLBACK (r13, 505 us) ======================
// =====================================================================

template<int KT, int ROWW>
__device__ __forceinline__ void layer_mfma(const unsigned short* sIn,
                                           const unsigned short* __restrict__ Wb,
                                           const float* __restrict__ bias,
                                           unsigned short* sOut,
                                           int wave, int lane)
{
  const int lcol = lane & 15;
  const int kg   = lane >> 4;
  const int lk   = kg * 8;
  const int colbase = wave * 64;
  const int swz = (lcol & 7) << 3;

  f32x4 acc[4][4];
  #pragma unroll
  for (int n = 0; n < 4; ++n) {
    const float bv = bias[colbase + n*16 + lcol];
    #pragma unroll
    for (int m = 0; m < 4; ++m) acc[m][n] = (f32x4){bv, bv, bv, bv};
  }
  const unsigned short* wpn[4];
  #pragma unroll
  for (int n = 0; n < 4; ++n)
    wpn[n] = Wb + (size_t)(colbase + n*16 + lcol)*(KT*32) + lk;

  bf16x8 a0[4], a1[4], b0[4], b1[4];
  #pragma unroll
  for (int n = 0; n < 4; ++n) b0[n] = *(const bf16x8*)(wpn[n]);
  #pragma unroll
  for (int n = 0; n < 4; ++n) b1[n] = *(const bf16x8*)(wpn[n] + 32);
  #pragma unroll
  for (int m = 0; m < 4; ++m)
    a0[m] = *(const bf16x8*)&sIn[(m*16 + lcol)*ROWW + (lk ^ swz)];

  #pragma unroll 1
  for (int kt = 0; kt < KT; kt += 2) {
    {
      const int k1 = (kt+1)*32 + lk;
      #pragma unroll
      for (int m = 0; m < 4; ++m)
        a1[m] = *(const bf16x8*)&sIn[(m*16 + lcol)*ROWW + (k1 ^ swz)];
    }
    #pragma unroll
    for (int n = 0; n < 4; ++n)
      #pragma unroll
      for (int m = 0; m < 4; ++m)
        acc[m][n] = __builtin_amdgcn_mfma_f32_16x16x32_bf16(a0[m], b0[n], acc[m][n], 0, 0, 0);
    if (kt + 2 < KT) {
      #pragma unroll
      for (int n = 0; n < 4; ++n) b0[n] = *(const bf16x8*)(wpn[n] + (kt+2)*32);
      const int k2 = (kt+2)*32 + lk;
      #pragma unroll
      for (int m = 0; m < 4; ++m)
        a0[m] = *(const bf16x8*)&sIn[(m*16 + lcol)*ROWW + (k2 ^ swz)];
    }
    #pragma unroll
    for (int n = 0; n < 4; ++n)
      #pragma unroll
      for (int m = 0; m < 4; ++m)
        acc[m][n] = __builtin_amdgcn_mfma_f32_16x16x32_bf16(a1[m], b1[n], acc[m][n], 0, 0, 0);
    if (kt + 3 < KT) {
      #pragma unroll
      for (int n = 0; n < 4; ++n) b1[n] = *(const bf16x8*)(wpn[n] + (kt+3)*32);
    }
  }

  __syncthreads();
  const int rbase = kg * 4;
  #pragma unroll
  for (int m = 0; m < 4; ++m)
    #pragma unroll
    for (int n = 0; n < 4; ++n) {
      const int col = colbase + n*16 + lcol;
      #pragma unroll
      for (int r = 0; r < 4; ++r) {
        const int row = m*16 + rbase + r;
        sOut[row*512 + (col ^ ((row & 7) << 3))] = f2b(fmaxf(acc[m][n][r], 0.f));
      }
    }
  __syncthreads();
}

__global__ void __launch_bounds__(512, 2)
vae_mfma(const float* __restrict__ initial_c, const float* __restrict__ initial_s,
         const float* __restrict__ current_c, const float* __restrict__ eps,
         const float* __restrict__ enc_b0, const float* __restrict__ enc_b1,
         const float* __restrict__ bm, const float* __restrict__ bv,
         const float* __restrict__ dec_b0, const float* __restrict__ dec_b1,
         const float* __restrict__ dec_b2, const unsigned short* __restrict__ ws,
         float* __restrict__ out)
{
  __shared__ __align__(16) unsigned short s_act[TM*512];
  __shared__ __align__(16) unsigned short s_in[TM*64];
  __shared__ float s_stage[3*TM*9];

  const int t = threadIdx.x;
  const int wave = t >> 6, lane = t & 63;
  const int lcol = lane & 15, kg = lane >> 4;
  const int lk = kg * 8, rbase = kg * 4;
  const int o     = blockIdx.x / NBT;
  const int bbase = (blockIdx.x % NBT) * TM;

  for (int s = t; s < TM*64; s += 512) {
    const int row = s >> 6, col = s & 63;
    float v = 0.f;
    if (col < 5)       v = (col == o) ? 1.f : 0.f;
    else if (col < 20) v = initial_s[(bbase+row)*15 + col - 5];
    else if (col < 32) v = initial_c[(bbase+row)*30 + d_OIDS[o][col-20]];
    else if (col < 44) v = current_c[(bbase+row)*30 + d_OIDS[o][col-32]];
    s_in[row*64 + (col ^ ((row & 7) << 3))] = f2b(v);
  }
  __syncthreads();

  layer_mfma<2, 64>  (s_in,  ws + UO_EW0, enc_b0, s_act, wave, lane);
  layer_mfma<16, 512>(s_act, ws + UO_EW1, enc_b1, s_act, wave, lane);

  {
    for (int s = t; s < TM*64; s += 512) {
      const int row = s >> 6, col = s & 63;
      if (col >= 5 && col < 14) continue;
      float v = 0.f;
      if (col < 5)       v = (col == o) ? 1.f : 0.f;
      else if (col < 29) v = initial_s[(bbase+row)*15 + col - 14];
      else if (col < 41) v = initial_c[(bbase+row)*30 + d_OIDS[o][col-29]];
      s_in[row*64 + (col ^ ((row & 7) << 3))] = f2b(v);
    }
    f32x4 am, av;
    if (wave < 4) {
      const float bmv = (lcol < 9) ? bm[lcol] : 0.f;
      const float bvv = (lcol < 9) ? bv[lcol] : 0.f;
      am = (f32x4){bmv, bmv, bmv, bmv};
      av = (f32x4){bvv, bvv, bvv, bvv};
      const unsigned short* hpM = ws + UO_HEADS + lcol*512 + lk;
      const unsigned short* hpV = hpM + 16*512;
      const int hrow = wave*16 + lcol;
      bf16x8 m0 = *(const bf16x8*)hpM;
      bf16x8 v0 = *(const bf16x8*)hpV;
      #pragma unroll 1
      for (int kt = 0; kt < 16; ++kt) {
        bf16x8 m1 = m0, v1 = v0;
        if (kt + 1 < 16) {
          m1 = *(const bf16x8*)(hpM + (kt+1)*32);
          v1 = *(const bf16x8*)(hpV + (kt+1)*32);
        }
        const int k0 = kt*32 + lk;
        bf16x8 a = *(const bf16x8*)&s_act[hrow*512 + (k0 ^ ((lcol & 7) << 3))];
        am = __builtin_amdgcn_mfma_f32_16x16x32_bf16(a, m0, am, 0, 0, 0);
        av = __builtin_amdgcn_mfma_f32_16x16x32_bf16(a, v0, av, 0, 0, 0);
        m0 = m1; v0 = v1;
      }
    }
    __syncthreads();
    if (wave < 4 && lcol < 9) {
      #pragma unroll
      for (int r = 0; r < 4; ++r) {
        const int row = wave*16 + rbase + r;
        const int gid = (o*BATCH + bbase + row)*9 + lcol;
        const float m_ = am[r], v_ = av[r];
        const float zz = fmaf(eps[gid], expf(0.5f*v_), m_);
        s_stage[        row*9 + lcol] = m_;
        s_stage[576 +   row*9 + lcol] = v_;
        s_stage[1152 +  row*9 + lcol] = zz;
        s_in[row*64 + ((5 + lcol) ^ ((row & 7) << 3))] = f2b(zz);
      }
    }
    __syncthreads();
    const int ob_m = OUT_MEANS + (o*BATCH + bbase)*9;
    const int ob_v = OUT_LV    + (o*BATCH + bbase)*9;
    const int ob_z = OUT_Z     + (o*BATCH + bbase)*9;
    for (int i = t; i < TM*9; i += 512) {
      __builtin_nontemporal_store(s_stage[i],        &out[ob_m + i]);
      __builtin_nontemporal_store(s_stage[576 + i],  &out[ob_v + i]);
      __builtin_nontemporal_store(s_stage[1152 + i], &out[ob_z + i]);
    }
  }

  layer_mfma<2, 64>  (s_in,  ws + UO_DW0, dec_b0, s_act, wave, lane);
  layer_mfma<16, 512>(s_act, ws + UO_DW1, dec_b1, s_act, wave, lane);

  if (wave < 4) {
    const float b2 = (lcol < 12) ? dec_b2[lcol] : 0.f;
    f32x4 acc = (f32x4){b2, b2, b2, b2};
    const unsigned short* wp = ws + UO_DW2 + lcol*512 + lk;
    const int hrow = wave*16 + lcol;
    bf16x8 b0 = *(const bf16x8*)wp;
    #pragma unroll 1
    for (int kt = 0; kt < 16; ++kt) {
      bf16x8 b1 = b0;
      if (kt + 1 < 16) b1 = *(const bf16x8*)(wp + (kt+1)*32);
      const int k0 = kt*32 + lk;
      bf16x8 a = *(const bf16x8*)&s_act[hrow*512 + (k0 ^ ((lcol & 7) << 3))];
      acc = __builtin_amdgcn_mfma_f32_16x16x32_bf16(a, b0, acc, 0, 0, 0);
      b0 = b1;
    }
    if (lcol < 12) {
      const int c30 = d_OIDS[o][lcol];
      #pragma unroll
      for (int r = 0; r < 4; ++r) {
        const int row = wave*16 + rbase + r;
        atomicAdd(&out[(bbase + row)*30 + c30], 1.f / (1.f + expf(-acc[r])));
      }
    }
  }
}

// ---------------- fallback (tiny ws): correct but slow fp32 ----------------
__global__ void __launch_bounds__(256)
vae_naive(const float* __restrict__ initial_c, const float* __restrict__ initial_s,
          const float* __restrict__ current_c, const float* __restrict__ eps,
          const float* eW0, const float* eb0, const float* eW1, const float* eb1,
          const float* Wm, const float* bm, const float* Wv, const float* bv,
          const float* dW0, const float* db0, const float* dW1, const float* db1,
          const float* dW2, const float* db2, float* out)
{
  __shared__ float xs[44], ds[41], h1[HID], h2[HID], rec[30];
  const int b = blockIdx.x, t = threadIdx.x;
  if (t < 30) rec[t] = 0.f;
  for (int o = 0; o < NOBJ; ++o) {
    __syncthreads();
    if (t < 44) {
      float v;
      if      (t < 5)  v = (t == o) ? 1.f : 0.f;
      else if (t < 20) v = initial_s[b*15 + (t-5)];
      else if (t < 32) v = initial_c[b*30 + d_OIDS[o][t-20]];
      else             v = current_c[b*30 + d_OIDS[o][t-32]];
      xs[t] = v;
    }
    __syncthreads();
    for (int h = t; h < HID; h += 256) {
      float a = eb0[h];
      for (int k = 0; k < 44; ++k) a = fmaf(xs[k], eW0[h*44+k], a);
      h1[h] = fmaxf(a, 0.f);
    }
    __syncthreads();
    for (int h = t; h < HID; h += 256) {
      float a = eb1[h];
      for (int k = 0; k < HID; ++k) a = fmaf(h1[k], eW1[h*512+k], a);
      h2[h] = fmaxf(a, 0.f);
    }
    __syncthreads();
    if (t < 9) {
      float am = bm[t], av = bv[t];
      for (int k = 0; k < HID; ++k) { am = fmaf(h2[k], Wm[t*512+k], am); av = fmaf(h2[k], Wv[t*512+k], av); }
      const int gid = (o*BATCH + b)*9 + t;
      out[OUT_MEANS + gid] = am;
      out[OUT_LV    + gid] = av;
      const float zz = fmaf(eps[gid], expf(0.5f*av), am);
      out[OUT_Z     + gid] = zz;
      ds[5+t] = zz;
    }
    if (t < 41 && (t < 5 || t >= 14)) {
      float v;
      if      (t < 5)  v = (t == o) ? 1.f : 0.f;
      else if (t < 29) v = initial_s[b*15 + (t-14)];
      else             v = initial_c[b*30 + d_OIDS[o][t-29]];
      ds[t] = v;
    }
    __syncthreads();
    for (int h = t; h < HID; h += 256) {
      float a = db0[h];
      for (int k = 0; k < 41; ++k) a = fmaf(ds[k], dW0[h*41+k], a);
      h1[h] = fmaxf(a, 0.f);
    }
    __syncthreads();
    for (int h = t; h < HID; h += 256) {
      float a = db1[h];
      for (int k = 0; k < HID; ++k) a = fmaf(h1[k], dW1[h*512+k], a);
      h2[h] = fmaxf(a, 0.f);
    }
    __syncthreads();
    if (t < 12) {
      float a = db2[t];
      for (int k = 0; k < HID; ++k) a = fmaf(h2[k], dW2[t*512+k], a);
      rec[d_OIDS[o][t]] += 1.f / (1.f + expf(-a));
    }
  }
  __syncthreads();
  if (t < 30) out[b*30+t] = rec[t];
}

extern "C" void kernel_launch(void* const* d_in, const int* in_sizes, int n_in,
                              void* d_out, int out_size, void* d_ws, size_t ws_size,
                              hipStream_t stream)
{
  const float* initial_c = (const float*)d_in[0];
  const float* initial_s = (const float*)d_in[1];
  const float* current_c = (const float*)d_in[2];
  const float* eps       = (const float*)d_in[3];
  const float* eW0 = (const float*)d_in[4];
  const float* eb0 = (const float*)d_in[5];
  const float* eW1 = (const float*)d_in[6];
  const float* eb1 = (const float*)d_in[7];
  const float* Wm  = (const float*)d_in[8];
  const float* bm  = (const float*)d_in[9];
  const float* Wv  = (const float*)d_in[10];
  const float* bv  = (const float*)d_in[11];
  const float* dW0 = (const float*)d_in[12];
  const float* db0 = (const float*)d_in[13];
  const float* dW1 = (const float*)d_in[14];
  const float* db1 = (const float*)d_in[15];
  const float* dW2 = (const float*)d_in[16];
  const float* db2 = (const float*)d_in[17];
  float* out = (float*)d_out;

  // layer-wise ws requirement: weights + XD(Mc*64) + H1,H2(Mc*512 each), ushort
  long long Mc = 0;
  if      (ws_size >= ((size_t)UO_TOTAL + 163840ULL*1088ULL) * 2ULL) Mc = 163840;
  else if (ws_size >= ((size_t)UO_TOTAL +  81920ULL*1088ULL) * 2ULL) Mc = 81920;

  if (Mc > 0) {
    unsigned short* ws = (unsigned short*)d_ws;
    prep_bf16<<<1024, 256, 0, stream>>>(eW0, eW1, Wm, Wv, dW0, dW1, dW2, ws);
    hipMemsetAsync(out, 0, (size_t)BATCH * 30 * sizeof(float), stream);
    unsigned short* XD = ws + UO_TOTAL;
    unsigned short* H1 = XD + (size_t)Mc*64;
    unsigned short* H2 = H1 + (size_t)Mc*512;
    const int nwg = (int)(Mc/128)*4;
    const int nib = (int)(Mc/64);
    const int nchunk = (int)(MTOT / Mc);
    for (int c = 0; c < nchunk; ++c) {
      const int M0 = (int)(c * Mc);
      enc_in_k  <<<nib, 256, 0, stream>>>(initial_c, initial_s, current_c, XD, M0);
      gemm_k<2> <<<nwg, 256, 0, stream>>>(XD, ws + UO_EW0, eb0, H1, nwg);
      dec_in_k  <<<nib, 256, 0, stream>>>(initial_c, initial_s, XD, M0);   // after X consumed
      gemm_k<16><<<nwg, 256, 0, stream>>>(H1, ws + UO_EW1, eb1, H2, nwg);
      heads_k   <<<nib, 256, 0, stream>>>(H2, XD, eps, bm, bv, ws, out, M0);
      gemm_k<2> <<<nwg, 256, 0, stream>>>(XD, ws + UO_DW0, db0, H1, nwg);
      gemm_k<16><<<nwg, 256, 0, stream>>>(H1, ws + UO_DW1, db1, H2, nwg);
      dec_head_k<<<nib, 256, 0, stream>>>(H2, ws, db2, out, M0);
    }
  } else if (ws_size >= (size_t)UO_TOTAL * sizeof(unsigned short)) {
    unsigned short* ws = (unsigned short*)d_ws;
    prep_bf16<<<1024, 256, 0, stream>>>(eW0, eW1, Wm, Wv, dW0, dW1, dW2, ws);
    hipMemsetAsync(out, 0, (size_t)BATCH * 30 * sizeof(float), stream);
    vae_mfma<<<NOBJ*NBT, 512, 0, stream>>>(initial_c, initial_s, current_c, eps,
                                           eb0, eb1, bm, bv, db0, db1, db2, ws, out);
  } else {
    vae_naive<<<BATCH, 256, 0, stream>>>(initial_c, initial_s, current_c, eps,
                                         eW0, eb0, eW1, eb1, Wm, bm, Wv, bv,
                                         dW0, db0, dW1, db1, dW2, db2, out);
  }
}

// Round 15
// 516.458 us; speedup vs baseline: 1.1708x; 1.1708x over previous
//
#include <hip/hip_runtime.h>
#include <math.h>

// ---------------- problem constants ----------------
#define BATCH 32768
#define HID   512
#define NOBJ  5
#define MTOT  (NOBJ*BATCH)   // 163840 total rows
#define TM    64             // fused-path rows per block
#define NBT   (BATCH/TM)

typedef __attribute__((ext_vector_type(8))) short bf16x8;
typedef __attribute__((ext_vector_type(4))) float f32x4;

typedef const __attribute__((address_space(1))) void* gas1_t;
typedef __attribute__((address_space(3))) void* las3_t;

__device__ __constant__ int d_OIDS[5][12] = {
  {0,1,2,3, 10,11,12,13,14,18,22,26},
  {0,4,5,6, 10,14,15,16,17,19,23,27},
  {1,4,7,8, 11,15,18,19,20,21,24,28},
  {2,5,7,9, 12,16,20,22,23,24,25,29},
  {3,6,8,9, 13,17,21,25,26,27,28,29}
};

// ---------------- bf16 weight workspace (ushort offsets) ----------------
#define UO_EW0   0                       // [512][64]  (K padded 44->64)
#define UO_EW1   (UO_EW0 + 512*64)       // [512][512]
#define UO_HEADS (UO_EW1 + 512*512)      // [32][512]: rows 0-8 Wm, 16-24 Wv
#define UO_DW0   (UO_HEADS + 32*512)     // [512][64]  (K padded 41->64)
#define UO_DW1   (UO_DW0 + 512*64)       // [512][512]
#define UO_DW2   (UO_DW1 + 512*512)      // [16][512]: rows 0-11 dec_W2
#define UO_TOTAL (UO_DW2 + 16*512)       // 614400 ushorts = 1.23 MB

// ---------------- output layout (floats) ----------------
#define OUT_MEANS (BATCH*30)
#define OUT_LV    (OUT_MEANS + NOBJ*BATCH*9)
#define OUT_Z     (OUT_LV    + NOBJ*BATCH*9)

__device__ __forceinline__ unsigned short f2b(float x) {
  unsigned int u = __builtin_bit_cast(unsigned int, x);
  u += 0x7FFFu + ((u >> 16) & 1u);
  return (unsigned short)(u >> 16);
}

// ---------------- prep: convert/pad weights into ws (bf16) ----------------
__global__ void __launch_bounds__(256)
prep_bf16(const float* __restrict__ eW0, const float* __restrict__ eW1,
          const float* __restrict__ Wm,  const float* __restrict__ Wv,
          const float* __restrict__ dW0, const float* __restrict__ dW1,
          const float* __restrict__ dW2, unsigned short* __restrict__ ws)
{
  for (int i = blockIdx.x*blockDim.x + threadIdx.x; i < UO_TOTAL; i += gridDim.x*blockDim.x) {
    float v = 0.f; int j;
    if (i < UO_EW1) {
      j = i - UO_EW0; int h = j >> 6, k = j & 63;
      if (k < 44) v = eW0[h*44 + k];
    } else if (i < UO_HEADS) {
      j = i - UO_EW1; v = eW1[j];
    } else if (i < UO_DW0) {
      j = i - UO_HEADS; int r = j >> 9, k = j & 511;
      if (r < 9)                  v = Wm[r*512 + k];
      else if (r >= 16 && r < 25) v = Wv[(r-16)*512 + k];
    } else if (i < UO_DW1) {
      j = i - UO_DW0; int h = j >> 6, k = j & 63;
      if (k < 41) v = dW0[h*41 + k];
    } else if (i < UO_DW2) {
      j = i - UO_DW1; v = dW1[j];
    } else {
      j = i - UO_DW2; int r = j >> 9, k = j & 511;
      if (r < 12) v = dW2[r*512 + k];
    }
    ws[i] = f2b(v);
  }
}

// =====================================================================
// ===================== LAYER-WISE PATH (big ws) ======================
// =====================================================================

// ---- stage one [128 rows][32 k] tile into LDS, conflict-free chunks ----
template<int KT>
__device__ __forceinline__ void stage_tile(const unsigned short* __restrict__ src,
                                           unsigned short* buf, int kt, int t)
{
  #pragma unroll
  for (int i = 0; i < 2; ++i) {
    const int c   = i*256 + t;
    const int row = ((c >> 6) << 4) | (c & 15);
    const int kg  = (c >> 4) & 3;
    const unsigned short* g = src + (size_t)row*(KT*32) + kt*32 + kg*8;
    unsigned short* l = buf + (size_t)(i*256 + (t & ~63)) * 8;
    __builtin_amdgcn_global_load_lds((gas1_t)g, (las3_t)l, 16, 0, 0);
  }
}

// C[Mc][512] = relu(A[Mc][KT*32] @ W[512][KT*32]^T + bias); bf16 C write.
template<int KT>
__global__ void __launch_bounds__(256, 2)
gemm_k(const unsigned short* __restrict__ A, const unsigned short* __restrict__ W,
       const float* __restrict__ bias, unsigned short* __restrict__ C, int nwg)
{
  __shared__ __align__(16) unsigned short sT[4*4096];  // A0 A1 B0 B1 (32 KB)

  const int t = threadIdx.x;
  const int wave = t >> 6, lane = t & 63;
  const int wm = wave >> 1, wn = wave & 1;
  const int lcol = lane & 15, kg = lane >> 4, rbase = kg*4;
  const int cpx = nwg >> 3;
  const int sid = ((int)blockIdx.x & 7)*cpx + ((int)blockIdx.x >> 3);
  const int mtile = sid >> 2, ntile = sid & 3;

  const unsigned short* Ab = A + (size_t)mtile*128*(KT*32);
  const unsigned short* Wb = W + (size_t)ntile*128*(KT*32);

  f32x4 acc[4][4];
  #pragma unroll
  for (int n = 0; n < 4; ++n) {
    const float bv = bias[ntile*128 + wn*64 + n*16 + lcol];
    #pragma unroll
    for (int m = 0; m < 4; ++m) acc[m][n] = (f32x4){bv, bv, bv, bv};
  }

  stage_tile<KT>(Ab, sT,          0, t);
  stage_tile<KT>(Wb, sT + 2*4096, 0, t);
  __syncthreads();

  int cur = 0;
  #pragma unroll 1
  for (int kt = 0; kt < KT; ++kt) {
    if (kt + 1 < KT) {
      stage_tile<KT>(Ab, sT + (cur^1)*4096,          kt+1, t);
      stage_tile<KT>(Wb, sT + 2*4096 + (cur^1)*4096, kt+1, t);
    }
    const unsigned short* bufA = sT + cur*4096;
    const unsigned short* bufB = sT + 2*4096 + cur*4096;
    bf16x8 a[4], b[4];
    #pragma unroll
    for (int m = 0; m < 4; ++m)
      a[m] = *(const bf16x8*)&bufA[(((wm*4+m)*4 + kg)*16 + lcol)*8];
    #pragma unroll
    for (int n = 0; n < 4; ++n)
      b[n] = *(const bf16x8*)&bufB[(((wn*4+n)*4 + kg)*16 + lcol)*8];
    #pragma unroll
    for (int n = 0; n < 4; ++n)
      #pragma unroll
      for (int m = 0; m < 4; ++m)
        acc[m][n] = __builtin_amdgcn_mfma_f32_16x16x32_bf16(a[m], b[n], acc[m][n], 0, 0, 0);
    __syncthreads();
    cur ^= 1;
  }

  unsigned short* sC = sT;
  #pragma unroll
  for (int m = 0; m < 4; ++m)
    #pragma unroll
    for (int n = 0; n < 4; ++n) {
      const int col = wn*64 + n*16 + lcol;
      #pragma unroll
      for (int r = 0; r < 4; ++r) {
        const int row = wm*64 + m*16 + rbase + r;
        sC[row*128 + (col ^ ((row & 7) << 3))] = f2b(fmaxf(acc[m][n][r], 0.f));
      }
    }
  __syncthreads();
  #pragma unroll
  for (int i = 0; i < 8; ++i) {
    const int g = i*256 + t;
    const int row = g >> 4, c0 = (g & 15)*8;
    bf16x8 v = *(const bf16x8*)&sC[row*128 + (c0 ^ ((row & 7) << 3))];
    *(bf16x8*)&C[(size_t)(mtile*128 + row)*512 + ntile*128 + c0] = v;
  }
}

// ---- big GEMM with fused head-partial epilogue (NO C write) ----
// NH=2: enc heads (Wm rows 0-8, Wv rows 16-24 of hw) -> PB[row][128]: slice
//       ntile at cols ntile*32 (+0..8 m-partial, +16..24 v-partial).
// NH=1: dec2 head (hw rows 0-11) -> PB[row][64]: slice at cols ntile*16.
template<int NH>
__global__ void __launch_bounds__(256, 2)
gemm_head_k(const unsigned short* __restrict__ A, const unsigned short* __restrict__ W,
            const float* __restrict__ bias, const unsigned short* __restrict__ hw,
            float* __restrict__ PB, int nwg)
{
  __shared__ __align__(16) unsigned short sT[4*4096];

  const int t = threadIdx.x;
  const int wave = t >> 6, lane = t & 63;
  const int wm = wave >> 1, wn = wave & 1;
  const int lcol = lane & 15, kg = lane >> 4, rbase = kg*4;
  const int cpx = nwg >> 3;
  const int sid = ((int)blockIdx.x & 7)*cpx + ((int)blockIdx.x >> 3);
  const int mtile = sid >> 2, ntile = sid & 3;

  const unsigned short* Ab = A + (size_t)mtile*128*512;
  const unsigned short* Wb = W + (size_t)ntile*128*512;

  f32x4 acc[4][4];
  #pragma unroll
  for (int n = 0; n < 4; ++n) {
    const float bv = bias[ntile*128 + wn*64 + n*16 + lcol];
    #pragma unroll
    for (int m = 0; m < 4; ++m) acc[m][n] = (f32x4){bv, bv, bv, bv};
  }

  stage_tile<16>(Ab, sT,          0, t);
  stage_tile<16>(Wb, sT + 2*4096, 0, t);
  __syncthreads();

  int cur = 0;
  #pragma unroll 1
  for (int kt = 0; kt < 16; ++kt) {
    if (kt + 1 < 16) {
      stage_tile<16>(Ab, sT + (cur^1)*4096,          kt+1, t);
      stage_tile<16>(Wb, sT + 2*4096 + (cur^1)*4096, kt+1, t);
    }
    const unsigned short* bufA = sT + cur*4096;
    const unsigned short* bufB = sT + 2*4096 + cur*4096;
    bf16x8 a[4], b[4];
    #pragma unroll
    for (int m = 0; m < 4; ++m)
      a[m] = *(const bf16x8*)&bufA[(((wm*4+m)*4 + kg)*16 + lcol)*8];
    #pragma unroll
    for (int n = 0; n < 4; ++n)
      b[n] = *(const bf16x8*)&bufB[(((wn*4+n)*4 + kg)*16 + lcol)*8];
    #pragma unroll
    for (int n = 0; n < 4; ++n)
      #pragma unroll
      for (int m = 0; m < 4; ++m)
        acc[m][n] = __builtin_amdgcn_mfma_f32_16x16x32_bf16(a[m], b[n], acc[m][n], 0, 0, 0);
    __syncthreads();
    cur ^= 1;
  }

  // relu'd bf16 tile -> LDS (the head MFMA's A source); no global C write
  unsigned short* sC = sT;
  #pragma unroll
  for (int m = 0; m < 4; ++m)
    #pragma unroll
    for (int n = 0; n < 4; ++n) {
      const int col = wn*64 + n*16 + lcol;
      #pragma unroll
      for (int r = 0; r < 4; ++r) {
        const int row = wm*64 + m*16 + rbase + r;
        sC[row*128 + (col ^ ((row & 7) << 3))] = f2b(fmaxf(acc[m][n][r], 0.f));
      }
    }
  __syncthreads();

  // head partial: PBpart[128 rows][NH*16 out] = tile @ hw[:, ntile*128..+128]^T
  // (each wave handles 2 M-tiles: waves cover m = wave*2, wave*2+1)
  f32x4 hacc[2][NH];
  #pragma unroll
  for (int m = 0; m < 2; ++m)
    #pragma unroll
    for (int h = 0; h < NH; ++h) hacc[m][h] = (f32x4){0.f, 0.f, 0.f, 0.f};

  #pragma unroll
  for (int ks = 0; ks < 4; ++ks) {
    const int kb = ks*32 + kg*8;
    bf16x8 bh[NH];
    #pragma unroll
    for (int h = 0; h < NH; ++h)
      bh[h] = *(const bf16x8*)&hw[(size_t)(h*16 + lcol)*512 + ntile*128 + kb];
    #pragma unroll
    for (int m = 0; m < 2; ++m) {
      const int row = (wave*2 + m)*16 + lcol;
      bf16x8 a = *(const bf16x8*)&sC[row*128 + (kb ^ ((row & 7) << 3))];
      #pragma unroll
      for (int h = 0; h < NH; ++h)
        hacc[m][h] = __builtin_amdgcn_mfma_f32_16x16x32_bf16(a, bh[h], hacc[m][h], 0, 0, 0);
    }
  }
  const int ROWF = NH*64;             // 128 (enc) or 64 (dec) floats per PB row
  #pragma unroll
  for (int m = 0; m < 2; ++m)
    #pragma unroll
    for (int h = 0; h < NH; ++h)
      #pragma unroll
      for (int r = 0; r < 4; ++r) {
        const int row = mtile*128 + (wave*2 + m)*16 + rbase + r;
        PB[(size_t)row*ROWF + ntile*(NH*16) + h*16 + lcol] = hacc[m][h][r];
      }
}

// ---- encoder input builder: X[lrow][64] = [oh|s|gi|gc|0] ----
__global__ void __launch_bounds__(256)
enc_in_k(const float* __restrict__ ic, const float* __restrict__ is_,
         const float* __restrict__ cc, unsigned short* __restrict__ X)
{
  #pragma unroll
  for (int i = 0; i < 16; ++i) {
    const int idx = i*256 + threadIdx.x;
    const int lrow = blockIdx.x*64 + (idx >> 6), col = idx & 63;
    const int o = lrow >> 15, b = lrow & 32767;
    float v = 0.f;
    if (col < 5)       v = (col == o) ? 1.f : 0.f;
    else if (col < 20) v = is_[b*15 + col - 5];
    else if (col < 32) v = ic[b*30 + d_OIDS[o][col-20]];
    else if (col < 44) v = cc[b*30 + d_OIDS[o][col-32]];
    X[(size_t)lrow*64 + col] = f2b(v);
  }
}

// ---- finalize heads: sum 4 slices, bias, z; write outs; build D (fused dec_in) ----
__global__ void __launch_bounds__(256)
fin_heads_k(const float* __restrict__ PB, const float* __restrict__ eps,
            const float* __restrict__ bm, const float* __restrict__ bv,
            const float* __restrict__ ic, const float* __restrict__ is_,
            unsigned short* __restrict__ D, float* __restrict__ out)
{
  __shared__ float s_z[64*9];
  const int t = threadIdx.x;
  const int lrow0 = blockIdx.x*64;
  for (int i = t; i < 576; i += 256) {
    const int lr = i/9, j = i - lr*9;
    const int row = lrow0 + lr;
    const float* pr = PB + (size_t)row*128;
    const float m_ = bm[j] + ((pr[j]    + pr[32+j]) + (pr[64+j] + pr[96+j]));
    const float v_ = bv[j] + ((pr[16+j] + pr[48+j]) + (pr[80+j] + pr[112+j]));
    const float zz = fmaf(eps[(size_t)row*9 + j], expf(0.5f*v_), m_);
    out[OUT_MEANS + (size_t)row*9 + j] = m_;
    out[OUT_LV    + (size_t)row*9 + j] = v_;
    out[OUT_Z     + (size_t)row*9 + j] = zz;
    s_z[lr*9 + j] = zz;
  }
  __syncthreads();
  #pragma unroll
  for (int i = 0; i < 16; ++i) {
    const int idx = i*256 + t;
    const int lr = idx >> 6, col = idx & 63;
    const int row = lrow0 + lr, o = row >> 15, b = row & 32767;
    float v = 0.f;
    if (col < 5)       v = (col == o) ? 1.f : 0.f;
    else if (col < 14) v = s_z[lr*9 + col - 5];
    else if (col < 29) v = is_[b*15 + col - 14];
    else if (col < 41) v = ic[b*30 + d_OIDS[o][col-29]];
    D[(size_t)row*64 + col] = f2b(v);
  }
}

// ---- finalize dec: sum 4 slices, bias, sigmoid, atomic scatter ----
__global__ void __launch_bounds__(256)
fin_dec_k(const float* __restrict__ PB, const float* __restrict__ db2,
          float* __restrict__ out)
{
  const int t = threadIdx.x;
  const int lrow0 = blockIdx.x*64;
  for (int i = t; i < 768; i += 256) {
    const int lr = i/12, j = i - lr*12;
    const int row = lrow0 + lr;
    const float* pr = PB + (size_t)row*64;
    const float a = db2[j] + ((pr[j] + pr[16+j]) + (pr[32+j] + pr[48+j]));
    const int o = row >> 15, b = row & 32767;
    atomicAdd(&out[b*30 + d_OIDS[o][j]], 1.f / (1.f + expf(-a)));
  }
}

// =====================================================================
// ================= FUSED FALLBACK (r13, 505 us) ======================
// =====================================================================

template<int KT, int ROWW>
__device__ __forceinline__ void layer_mfma(const unsigned short* sIn,
                                           const unsigned short* __restrict__ Wb,
                                           const float* __restrict__ bias,
                                           unsigned short* sOut,
                                           int wave, int lane)
{
  const int lcol = lane & 15;
  const int kg   = lane >> 4;
  const int lk   = kg * 8;
  const int colbase = wave * 64;
  const int swz = (lcol & 7) << 3;

  f32x4 acc[4][4];
  #pragma unroll
  for (int n = 0; n < 4; ++n) {
    const float bv = bias[colbase + n*16 + lcol];
    #pragma unroll
    for (int m = 0; m < 4; ++m) acc[m][n] = (f32x4){bv, bv, bv, bv};
  }
  const unsigned short* wpn[4];
  #pragma unroll
  for (int n = 0; n < 4; ++n)
    wpn[n] = Wb + (size_t)(colbase + n*16 + lcol)*(KT*32) + lk;

  bf16x8 a0[4], a1[4], b0[4], b1[4];
  #pragma unroll
  for (int n = 0; n < 4; ++n) b0[n] = *(const bf16x8*)(wpn[n]);
  #pragma unroll
  for (int n = 0; n < 4; ++n) b1[n] = *(const bf16x8*)(wpn[n] + 32);
  #pragma unroll
  for (int m = 0; m < 4; ++m)
    a0[m] = *(const bf16x8*)&sIn[(m*16 + lcol)*ROWW + (lk ^ swz)];

  #pragma unroll 1
  for (int kt = 0; kt < KT; kt += 2) {
    {
      const int k1 = (kt+1)*32 + lk;
      #pragma unroll
      for (int m = 0; m < 4; ++m)
        a1[m] = *(const bf16x8*)&sIn[(m*16 + lcol)*ROWW + (k1 ^ swz)];
    }
    #pragma unroll
    for (int n = 0; n < 4; ++n)
      #pragma unroll
      for (int m = 0; m < 4; ++m)
        acc[m][n] = __builtin_amdgcn_mfma_f32_16x16x32_bf16(a0[m], b0[n], acc[m][n], 0, 0, 0);
    if (kt + 2 < KT) {
      #pragma unroll
      for (int n = 0; n < 4; ++n) b0[n] = *(const bf16x8*)(wpn[n] + (kt+2)*32);
      const int k2 = (kt+2)*32 + lk;
      #pragma unroll
      for (int m = 0; m < 4; ++m)
        a0[m] = *(const bf16x8*)&sIn[(m*16 + lcol)*ROWW + (k2 ^ swz)];
    }
    #pragma unroll
    for (int n = 0; n < 4; ++n)
      #pragma unroll
      for (int m = 0; m < 4; ++m)
        acc[m][n] = __builtin_amdgcn_mfma_f32_16x16x32_bf16(a1[m], b1[n], acc[m][n], 0, 0, 0);
    if (kt + 3 < KT) {
      #pragma unroll
      for (int n = 0; n < 4; ++n) b1[n] = *(const bf16x8*)(wpn[n] + (kt+3)*32);
    }
  }

  __syncthreads();
  const int rbase = kg * 4;
  #pragma unroll
  for (int m = 0; m < 4; ++m)
    #pragma unroll
    for (int n = 0; n < 4; ++n) {
      const int col = colbase + n*16 + lcol;
      #pragma unroll
      for (int r = 0; r < 4; ++r) {
        const int row = m*16 + rbase + r;
        sOut[row*512 + (col ^ ((row & 7) << 3))] = f2b(fmaxf(acc[m][n][r], 0.f));
      }
    }
  __syncthreads();
}

__global__ void __launch_bounds__(512, 2)
vae_mfma(const float* __restrict__ initial_c, const float* __restrict__ initial_s,
         const float* __restrict__ current_c, const float* __restrict__ eps,
         const float* __restrict__ enc_b0, const float* __restrict__ enc_b1,
         const float* __restrict__ bm, const float* __restrict__ bv,
         const float* __restrict__ dec_b0, const float* __restrict__ dec_b1,
         const float* __restrict__ dec_b2, const unsigned short* __restrict__ ws,
         float* __restrict__ out)
{
  __shared__ __align__(16) unsigned short s_act[TM*512];
  __shared__ __align__(16) unsigned short s_in[TM*64];
  __shared__ float s_stage[3*TM*9];

  const int t = threadIdx.x;
  const int wave = t >> 6, lane = t & 63;
  const int lcol = lane & 15, kg = lane >> 4;
  const int lk = kg * 8, rbase = kg * 4;
  const int o     = blockIdx.x / NBT;
  const int bbase = (blockIdx.x % NBT) * TM;

  for (int s = t; s < TM*64; s += 512) {
    const int row = s >> 6, col = s & 63;
    float v = 0.f;
    if (col < 5)       v = (col == o) ? 1.f : 0.f;
    else if (col < 20) v = initial_s[(bbase+row)*15 + col - 5];
    else if (col < 32) v = initial_c[(bbase+row)*30 + d_OIDS[o][col-20]];
    else if (col < 44) v = current_c[(bbase+row)*30 + d_OIDS[o][col-32]];
    s_in[row*64 + (col ^ ((row & 7) << 3))] = f2b(v);
  }
  __syncthreads();

  layer_mfma<2, 64>  (s_in,  ws + UO_EW0, enc_b0, s_act, wave, lane);
  layer_mfma<16, 512>(s_act, ws + UO_EW1, enc_b1, s_act, wave, lane);

  {
    for (int s = t; s < TM*64; s += 512) {
      const int row = s >> 6, col = s & 63;
      if (col >= 5 && col < 14) continue;
      float v = 0.f;
      if (col < 5)       v = (col == o) ? 1.f : 0.f;
      else if (col < 29) v = initial_s[(bbase+row)*15 + col - 14];
      else if (col < 41) v = initial_c[(bbase+row)*30 + d_OIDS[o][col-29]];
      s_in[row*64 + (col ^ ((row & 7) << 3))] = f2b(v);
    }
    f32x4 am, av;
    if (wave < 4) {
      const float bmv = (lcol < 9) ? bm[lcol] : 0.f;
      const float bvv = (lcol < 9) ? bv[lcol] : 0.f;
      am = (f32x4){bmv, bmv, bmv, bmv};
      av = (f32x4){bvv, bvv, bvv, bvv};
      const unsigned short* hpM = ws + UO_HEADS + lcol*512 + lk;
      const unsigned short* hpV = hpM + 16*512;
      const int hrow = wave*16 + lcol;
      bf16x8 m0 = *(const bf16x8*)hpM;
      bf16x8 v0 = *(const bf16x8*)hpV;
      #pragma unroll 1
      for (int kt = 0; kt < 16; ++kt) {
        bf16x8 m1 = m0, v1 = v0;
        if (kt + 1 < 16) {
          m1 = *(const bf16x8*)(hpM + (kt+1)*32);
          v1 = *(const bf16x8*)(hpV + (kt+1)*32);
        }
        const int k0 = kt*32 + lk;
        bf16x8 a = *(const bf16x8*)&s_act[hrow*512 + (k0 ^ ((lcol & 7) << 3))];
        am = __builtin_amdgcn_mfma_f32_16x16x32_bf16(a, m0, am, 0, 0, 0);
        av = __builtin_amdgcn_mfma_f32_16x16x32_bf16(a, v0, av, 0, 0, 0);
        m0 = m1; v0 = v1;
      }
    }
    __syncthreads();
    if (wave < 4 && lcol < 9) {
      #pragma unroll
      for (int r = 0; r < 4; ++r) {
        const int row = wave*16 + rbase + r;
        const int gid = (o*BATCH + bbase + row)*9 + lcol;
        const float m_ = am[r], v_ = av[r];
        const float zz = fmaf(eps[gid], expf(0.5f*v_), m_);
        s_stage[        row*9 + lcol] = m_;
        s_stage[576 +   row*9 + lcol] = v_;
        s_stage[1152 +  row*9 + lcol] = zz;
        s_in[row*64 + ((5 + lcol) ^ ((row & 7) << 3))] = f2b(zz);
      }
    }
    __syncthreads();
    const int ob_m = OUT_MEANS + (o*BATCH + bbase)*9;
    const int ob_v = OUT_LV    + (o*BATCH + bbase)*9;
    const int ob_z = OUT_Z     + (o*BATCH + bbase)*9;
    for (int i = t; i < TM*9; i += 512) {
      __builtin_nontemporal_store(s_stage[i],        &out[ob_m + i]);
      __builtin_nontemporal_store(s_stage[576 + i],  &out[ob_v + i]);
      __builtin_nontemporal_store(s_stage[1152 + i], &out[ob_z + i]);
    }
  }

  layer_mfma<2, 64>  (s_in,  ws + UO_DW0, dec_b0, s_act, wave, lane);
  layer_mfma<16, 512>(s_act, ws + UO_DW1, dec_b1, s_act, wave, lane);

  if (wave < 4) {
    const float b2 = (lcol < 12) ? dec_b2[lcol] : 0.f;
    f32x4 acc = (f32x4){b2, b2, b2, b2};
    const unsigned short* wp = ws + UO_DW2 + lcol*512 + lk;
    const int hrow = wave*16 + lcol;
    bf16x8 b0 = *(const bf16x8*)wp;
    #pragma unroll 1
    for (int kt = 0; kt < 16; ++kt) {
      bf16x8 b1 = b0;
      if (kt + 1 < 16) b1 = *(const bf16x8*)(wp + (kt+1)*32);
      const int k0 = kt*32 + lk;
      bf16x8 a = *(const bf16x8*)&s_act[hrow*512 + (k0 ^ ((lcol & 7) << 3))];
      acc = __builtin_amdgcn_mfma_f32_16x16x32_bf16(a, b0, acc, 0, 0, 0);
      b0 = b1;
    }
    if (lcol < 12) {
      const int c30 = d_OIDS[o][lcol];
      #pragma unroll
      for (int r = 0; r < 4; ++r) {
        const int row = wave*16 + rbase + r;
        atomicAdd(&out[(bbase + row)*30 + c30], 1.f / (1.f + expf(-acc[r])));
      }
    }
  }
}

// ---------------- fallback (tiny ws): correct but slow fp32 ----------------
__global__ void __launch_bounds__(256)
vae_naive(const float* __restrict__ initial_c, const float* __restrict__ initial_s,
          const float* __restrict__ current_c, const float* __restrict__ eps,
          const float* eW0, const float* eb0, const float* eW1, const float* eb1,
          const float* Wm, const float* bm, const float* Wv, const float* bv,
          const float* dW0, const float* db0, const float* dW1, const float* db1,
          const float* dW2, const float* db2, float* out)
{
  __shared__ float xs[44], ds[41], h1[HID], h2[HID], rec[30];
  const int b = blockIdx.x, t = threadIdx.x;
  if (t < 30) rec[t] = 0.f;
  for (int o = 0; o < NOBJ; ++o) {
    __syncthreads();
    if (t < 44) {
      float v;
      if      (t < 5)  v = (t == o) ? 1.f : 0.f;
      else if (t < 20) v = initial_s[b*15 + (t-5)];
      else if (t < 32) v = initial_c[b*30 + d_OIDS[o][t-20]];
      else             v = current_c[b*30 + d_OIDS[o][t-32]];
      xs[t] = v;
    }
    __syncthreads();
    for (int h = t; h < HID; h += 256) {
      float a = eb0[h];
      for (int k = 0; k < 44; ++k) a = fmaf(xs[k], eW0[h*44+k], a);
      h1[h] = fmaxf(a, 0.f);
    }
    __syncthreads();
    for (int h = t; h < HID; h += 256) {
      float a = eb1[h];
      for (int k = 0; k < HID; ++k) a = fmaf(h1[k], eW1[h*512+k], a);
      h2[h] = fmaxf(a, 0.f);
    }
    __syncthreads();
    if (t < 9) {
      float am = bm[t], av = bv[t];
      for (int k = 0; k < HID; ++k) { am = fmaf(h2[k], Wm[t*512+k], am); av = fmaf(h2[k], Wv[t*512+k], av); }
      const int gid = (o*BATCH + b)*9 + t;
      out[OUT_MEANS + gid] = am;
      out[OUT_LV    + gid] = av;
      const float zz = fmaf(eps[gid], expf(0.5f*av), am);
      out[OUT_Z     + gid] = zz;
      ds[5+t] = zz;
    }
    if (t < 41 && (t < 5 || t >= 14)) {
      float v;
      if      (t < 5)  v = (t == o) ? 1.f : 0.f;
      else if (t < 29) v = initial_s[b*15 + (t-14)];
      else             v = initial_c[b*30 + d_OIDS[o][t-29]];
      ds[t] = v;
    }
    __syncthreads();
    for (int h = t; h < HID; h += 256) {
      float a = db0[h];
      for (int k = 0; k < 41; ++k) a = fmaf(ds[k], dW0[h*41+k], a);
      h1[h] = fmaxf(a, 0.f);
    }
    __syncthreads();
    for (int h = t; h < HID; h += 256) {
      float a = db1[h];
      for (int k = 0; k < HID; ++k) a = fmaf(h1[k], dW1[h*512+k], a);
      h2[h] = fmaxf(a, 0.f);
    }
    __syncthreads();
    if (t < 12) {
      float a = db2[t];
      for (int k = 0; k < HID; ++k) a = fmaf(h2[k], dW2[t*512+k], a);
      rec[d_OIDS[o][t]] += 1.f / (1.f + expf(-a));
    }
  }
  __syncthreads();
  if (t < 30) out[b*30+t] = rec[t];
}

extern "C" void kernel_launch(void* const* d_in, const int* in_sizes, int n_in,
                              void* d_out, int out_size, void* d_ws, size_t ws_size,
                              hipStream_t stream)
{
  const float* initial_c = (const float*)d_in[0];
  const float* initial_s = (const float*)d_in[1];
  const float* current_c = (const float*)d_in[2];
  const float* eps       = (const float*)d_in[3];
  const float* eW0 = (const float*)d_in[4];
  const float* eb0 = (const float*)d_in[5];
  const float* eW1 = (const float*)d_in[6];
  const float* eb1 = (const float*)d_in[7];
  const float* Wm  = (const float*)d_in[8];
  const float* bm  = (const float*)d_in[9];
  const float* Wv  = (const float*)d_in[10];
  const float* bv  = (const float*)d_in[11];
  const float* dW0 = (const float*)d_in[12];
  const float* db0 = (const float*)d_in[13];
  const float* dW1 = (const float*)d_in[14];
  const float* db1 = (const float*)d_in[15];
  const float* dW2 = (const float*)d_in[16];
  const float* db2 = (const float*)d_in[17];
  float* out = (float*)d_out;

  // layer-wise ws: weights + XD(M*64) + H1(M*512) + PB(M*128 f32 = M*256 us)
  const size_t need = ((size_t)UO_TOTAL + (size_t)MTOT*(64 + 512 + 256)) * 2ULL;

  if (ws_size >= need) {
    unsigned short* ws = (unsigned short*)d_ws;
    prep_bf16<<<1024, 256, 0, stream>>>(eW0, eW1, Wm, Wv, dW0, dW1, dW2, ws);
    hipMemsetAsync(out, 0, (size_t)BATCH * 30 * sizeof(float), stream);
    unsigned short* XD = ws + UO_TOTAL;
    unsigned short* H1 = XD + (size_t)MTOT*64;
    float*          PB = (float*)(H1 + (size_t)MTOT*512);
    const int nwg = (MTOT/128)*4;      // 5120, %8==0
    const int nib = MTOT/64;           // 2560
    enc_in_k     <<<nib, 256, 0, stream>>>(initial_c, initial_s, current_c, XD);
    gemm_k<2>    <<<nwg, 256, 0, stream>>>(XD, ws + UO_EW0, eb0, H1, nwg);
    gemm_head_k<2><<<nwg, 256, 0, stream>>>(H1, ws + UO_EW1, eb1, ws + UO_HEADS, PB, nwg);
    fin_heads_k  <<<nib, 256, 0, stream>>>(PB, eps, bm, bv, initial_c, initial_s, XD, out);
    gemm_k<2>    <<<nwg, 256, 0, stream>>>(XD, ws + UO_DW0, db0, H1, nwg);
    gemm_head_k<1><<<nwg, 256, 0, stream>>>(H1, ws + UO_DW1, db1, ws + UO_DW2, PB, nwg);
    fin_dec_k    <<<nib, 256, 0, stream>>>(PB, db2, out);
  } else if (ws_size >= (size_t)UO_TOTAL * sizeof(unsigned short)) {
    unsigned short* ws = (unsigned short*)d_ws;
    prep_bf16<<<1024, 256, 0, stream>>>(eW0, eW1, Wm, Wv, dW0, dW1, dW2, ws);
    hipMemsetAsync(out, 0, (size_t)BATCH * 30 * sizeof(float), stream);
    vae_mfma<<<NOBJ*NBT, 512, 0, stream>>>(initial_c, initial_s, current_c, eps,
                                           eb0, eb1, bm, bv, db0, db1, db2, ws, out);
  } else {
    vae_naive<<<BATCH, 256, 0, stream>>>(initial_c, initial_s, current_c, eps,
                                         eW0, eb0, eW1, eb1, Wm, bm, Wv, bv,
                                         dW0, db0, dW1, db1, dW2, db2, out);
  }
}